// Round 24
// baseline (32.512 us; speedup 1.0000x reference)
//
#include <hip/hip_runtime.h>

#define T_FRAMES 256
#define D_IN 80
#define CCH 256
#define CCEP 222
#define FFT_N 1024
#define HOP 256
#define WINL 512
#define PF_KT 128
#define ZLEN 65536

__device__ __forceinline__ unsigned br10(unsigned x) { return __brev(x) >> 22; }

// =============== shared conv inner loop (512 thr: c = tid&255, fh = tid>>8, 8 frames each) ===============
__device__ __forceinline__ void conv_inner(const float4* __restrict__ wlds4,
                                           const float4* __restrict__ inlds4,
                                           int c, int fh, float* __restrict__ acc) {
  #pragma unroll
  for (int cg = 0; cg < 4; ++cg) {
    float4 w0 = wlds4[(cg * 3 + 0) * 256 + c];
    float4 w1v = wlds4[(cg * 3 + 1) * 256 + c];
    float4 w2v = wlds4[(cg * 3 + 2) * 256 + c];
    float4 xr[10];
    #pragma unroll
    for (int r = 0; r < 10; ++r) xr[r] = inlds4[(fh * 8 + r) * 4 + cg];
    #pragma unroll
    for (int j = 0; j < 8; ++j) {
      float4 xa = xr[j], xb = xr[j + 1], xc = xr[j + 2];
      acc[j] += xa.x * w0.x  + xb.x * w0.y  + xc.x * w0.z
              + xa.y * w0.w  + xb.y * w1v.x + xc.y * w1v.y
              + xa.z * w1v.z + xb.z * w1v.w + xc.z * w2v.x
              + xa.w * w2v.y + xb.w * w2v.z + xc.w * w2v.w;
    }
  }
}

// ---- K_A: fused conv1+conv2. grid (16 kc, 16 g) — R22 verbatim ----
__global__ __launch_bounds__(512) void conv12_k(const float* __restrict__ x, const float* __restrict__ w1,
                                                const float* __restrict__ b1, const float* __restrict__ w2,
                                                float* __restrict__ h2p) {
  __shared__ float4 wlds4[12 * 256];   // w2 slice, 48 KB
  __shared__ float  w1lds[240 * 17];   // w1 slice, pitch 17 (conflict-free), 16 KB
  __shared__ float4 xlds4[20 * 20];    // x frames t0-2..t0+17
  __shared__ float4 inlds4[18 * 4];    // h1 chunk
  const int kc = blockIdx.x, g = blockIdx.y, tid = threadIdx.x;
  const int t0 = g << 4;
  const float4* w24 = (const float4*)w2;
  const float4* x4 = (const float4*)x;
  {
    const int row = tid & 255, seg = tid >> 8;
    const float4* src = w24 + row * 192 + kc * 12 + seg * 6;
    #pragma unroll
    for (int m = 0; m < 6; ++m) wlds4[(seg * 6 + m) * 256 + row] = src[m];
  }
  for (int idx = tid; idx < 3840; idx += 512) {
    int ch = idx / 240, j = idx - ch * 240;
    w1lds[j * 17 + ch] = w1[(kc * 16 + ch) * 240 + j];
  }
  if (tid < 400) {
    int f = tid / 20, cg = tid - f * 20;
    int tt = t0 - 2 + f;
    xlds4[f * 20 + cg] = (tt >= 0 && tt < T_FRAMES) ? x4[tt * 20 + cg] : make_float4(0.f, 0.f, 0.f, 0.f);
  }
  __syncthreads();
  if (tid < 288) {
    int f = tid >> 4, ch = tid & 15;
    int tt = t0 - 1 + f;
    float acc = b1[kc * 16 + ch];
    const float* x0 = (const float*)&xlds4[(f + 0) * 20];
    const float* x1 = (const float*)&xlds4[(f + 1) * 20];
    const float* x2 = (const float*)&xlds4[(f + 2) * 20];
    #pragma unroll 8
    for (int cin = 0; cin < D_IN; ++cin) {
      acc += x0[cin] * w1lds[(cin * 3 + 0) * 17 + ch]
           + x1[cin] * w1lds[(cin * 3 + 1) * 17 + ch]
           + x2[cin] * w1lds[(cin * 3 + 2) * 17 + ch];
    }
    ((float*)inlds4)[f * 16 + ch] = (tt >= 0 && tt < T_FRAMES) ? fmaxf(acc, 0.f) : 0.f;
  }
  __syncthreads();
  const int c = tid & 255, fh = tid >> 8;
  float acc[8] = {0.f, 0.f, 0.f, 0.f, 0.f, 0.f, 0.f, 0.f};
  conv_inner(wlds4, inlds4, c, fh, acc);
  const int ob = kc << 8;
  #pragma unroll
  for (int j = 0; j < 8; ++j) h2p[(ob + t0 + fh * 8 + j) * CCH + c] = acc[j];
}

// ---- K_B: conv3 partials. grid (16 kc, 16 g) — R22 verbatim ----
__global__ __launch_bounds__(512) void conv3_k(const float* __restrict__ h2p, const float* __restrict__ b2,
                                               const float* __restrict__ w3, float* __restrict__ ccp) {
  __shared__ float4 wlds4[12 * 256];
  __shared__ float4 sred4[72 * 4];
  __shared__ float4 inlds4[18 * 4];
  const int kc = blockIdx.x, g = blockIdx.y, tid = threadIdx.x;
  const int t0 = g << 4;
  const float4* w34 = (const float4*)w3;
  const float4* h2p4 = (const float4*)h2p;
  const float4* b24 = (const float4*)b2;
  {
    const int row = tid & 255, seg = tid >> 8;
    if (row < CCEP) {
      const float4* src = w34 + row * 192 + kc * 12 + seg * 6;
      #pragma unroll
      for (int m = 0; m < 6; ++m) wlds4[(seg * 6 + m) * 256 + row] = src[m];
    }
  }
  if (tid < 288) {
    int e = tid >> 2, q = tid & 3;
    int r = e >> 2, cg = e & 3;
    int tt = t0 - 1 + r;
    float4 v = make_float4(0.f, 0.f, 0.f, 0.f);
    if (tt >= 0 && tt < T_FRAMES) {
      #pragma unroll
      for (int pp = 0; pp < 4; ++pp) {
        float4 a = h2p4[(((q * 4 + pp) << 8) + tt) * 64 + kc * 4 + cg];
        v.x += a.x; v.y += a.y; v.z += a.z; v.w += a.w;
      }
    }
    sred4[e * 4 + q] = v;
  }
  __syncthreads();
  if (tid < 72) {
    int r = tid >> 2, cg = tid & 3, tt = t0 - 1 + r;
    float4 s = make_float4(0.f, 0.f, 0.f, 0.f);
    if (tt >= 0 && tt < T_FRAMES) {
      s = b24[kc * 4 + cg];
      #pragma unroll
      for (int q = 0; q < 4; ++q) {
        float4 v = sred4[tid * 4 + q];
        s.x += v.x; s.y += v.y; s.z += v.z; s.w += v.w;
      }
      s.x = fmaxf(s.x, 0.f); s.y = fmaxf(s.y, 0.f); s.z = fmaxf(s.z, 0.f); s.w = fmaxf(s.w, 0.f);
    }
    inlds4[tid] = s;
  }
  __syncthreads();
  const int c = tid & 255, fh = tid >> 8;
  if (c < CCEP) {
    float acc[8] = {0.f, 0.f, 0.f, 0.f, 0.f, 0.f, 0.f, 0.f};
    conv_inner(wlds4, inlds4, c, fh, acc);
    const int ob = kc << 8;
    #pragma unroll
    for (int j = 0; j < 8; ++j) ccp[(ob + t0 + fh * 8 + j) * CCEP + c] = acc[j];
  }
}

// ---- K_C: fused spectral kernel. NEW: 2 frames/block (grid 128) — full round occupancy
//      with radix-4 fused passes: frame fr = tid>>8, group gid = tid&255 ----
__global__ __launch_bounds__(512) void fftltv_k(const float* __restrict__ ccp, const float* __restrict__ b3,
                                                const float* __restrict__ quef, const float* __restrict__ z,
                                                const float* __restrict__ win, float* __restrict__ outw) {
  __shared__ float2 U[2][FFT_N];    // 16 KB
  __shared__ float ccs[2][224];
  __shared__ float zlds[2][512];
  __shared__ float sout[2][512];
  const int t0 = blockIdx.x * 2, tid = threadIdx.x;
  // coalesced ccp reduction for both frames (f = tid>>8, c = tid&255)
  {
    int f = tid >> 8, c = tid & 255;
    if (c < CCEP) {
      float s = b3[c];
      #pragma unroll
      for (int p = 0; p < 16; ++p) s += ccp[((p << 8) + t0 + f) * CCEP + c];
      ccs[f][c] = s / quef[c];
    }
  }
  #pragma unroll
  for (int f = 0; f < 2; ++f) {
    int idx = (t0 + f) * HOP + tid - 255;
    zlds[f][tid] = (idx >= 0 && idx < ZLEN) ? z[idx] : 0.f;
  }
  __syncthreads();
  #pragma unroll
  for (int f = 0; f < 2; ++f) {
    for (int i = tid; i < FFT_N; i += 512) {
      unsigned q = br10((unsigned)i);
      float a = (q >= 401u && q < 623u) ? ccs[f][q - 401u] : 0.f;
      float bv = (q < 512u) ? zlds[f][q] : 0.f;
      U[f][i] = make_float2(a, bv);
    }
  }
  __syncthreads();
  const int fr = tid >> 8, gid = tid & 255;
  float2* Uf = U[fr];
  // forward DIT, radix-4 fused passes — all 512 threads active per round
  #pragma unroll
  for (int s = 1; s <= 10; s += 2) {
    {
      int h = 1 << (s - 1);
      int pos = gid & (h - 1);
      int a = ((gid >> (s - 1)) << (s + 1)) + pos;
      float2 e0 = Uf[a], e1 = Uf[a + h], e2 = Uf[a + 2 * h], e3 = Uf[a + 3 * h];
      float s1, c1; __sincosf((-6.283185307179586f / (float)(2 * h)) * (float)pos, &s1, &c1);
      float s2, c2; __sincosf((-6.283185307179586f / (float)(4 * h)) * (float)pos, &s2, &c2);
      float2 t1 = make_float2(c1 * e1.x - s1 * e1.y, c1 * e1.y + s1 * e1.x);
      float2 t3 = make_float2(c1 * e3.x - s1 * e3.y, c1 * e3.y + s1 * e3.x);
      float2 A0 = make_float2(e0.x + t1.x, e0.y + t1.y);
      float2 A1 = make_float2(e0.x - t1.x, e0.y - t1.y);
      float2 A2 = make_float2(e2.x + t3.x, e2.y + t3.y);
      float2 A3 = make_float2(e2.x - t3.x, e2.y - t3.y);
      float2 u2 = make_float2(c2 * A2.x - s2 * A2.y, c2 * A2.y + s2 * A2.x);
      float2 u3 = make_float2(s2 * A3.x + c2 * A3.y, s2 * A3.y - c2 * A3.x);
      Uf[a]         = make_float2(A0.x + u2.x, A0.y + u2.y);
      Uf[a + 2 * h] = make_float2(A0.x - u2.x, A0.y - u2.y);
      Uf[a + h]     = make_float2(A1.x + u3.x, A1.y + u3.y);
      Uf[a + 3 * h] = make_float2(A1.x - u3.x, A1.y - u3.y);
    }
    __syncthreads();
  }
  // pointwise spectral transform for both frames (j = tid per frame)
  {
    auto pcalc = [](float2 Uj, float2 Um) -> float2 {
      float Ar = 0.5f * (Uj.x + Um.x);
      float Ai = 0.5f * (Uj.y - Um.y);
      float Bx = 0.5f * (Uj.y + Um.y);
      float By = 0.5f * (Um.x - Uj.x);
      float mag = __expf(0.23025850929940457f * Ar);
      float sn, cs; __sincosf(Ai, &sn, &cs);
      float SPx = mag * cs, SPy = mag * sn;
      return make_float2(Bx * SPx + By * SPy, Bx * SPy - By * SPx);
    };
    int j = tid;
    int mj = (FFT_N - j) & (FFT_N - 1);
    float2 Pj[2], P5[2];
    #pragma unroll
    for (int f = 0; f < 2; ++f) {
      float2 Uj = U[f][j], Um = U[f][mj];
      Pj[f] = pcalc(Uj, Um);
      if (tid == 0) { float2 U5 = U[f][512]; P5[f] = pcalc(U5, U5); }
    }
    __syncthreads();
    #pragma unroll
    for (int f = 0; f < 2; ++f) {
      U[f][j] = Pj[f];
      if (tid == 0) U[f][512] = P5[f];
      else U[f][mj] = make_float2(Pj[f].x, -Pj[f].y);
    }
  }
  __syncthreads();
  // inverse DIF, radix-4 fused passes — all 512 threads active per round
  #pragma unroll
  for (int s = 10; s >= 2; s -= 2) {
    {
      int H = 1 << (s - 1);
      int Hh = H >> 1;
      int pos = gid & (Hh - 1);
      int a = ((gid >> (s - 2)) << s) + pos;
      float2 e0 = Uf[a], e1 = Uf[a + Hh], e2 = Uf[a + H], e3 = Uf[a + H + Hh];
      float s1, c1; __sincosf((6.283185307179586f / (float)(2 * H)) * (float)pos, &s1, &c1);
      float s2, c2; __sincosf((6.283185307179586f / (float)H) * (float)pos, &s2, &c2);
      float2 A0 = make_float2(e0.x + e2.x, e0.y + e2.y);
      float2 d02 = make_float2(e0.x - e2.x, e0.y - e2.y);
      float2 A2 = make_float2(c1 * d02.x - s1 * d02.y, c1 * d02.y + s1 * d02.x);
      float2 A1 = make_float2(e1.x + e3.x, e1.y + e3.y);
      float2 d13 = make_float2(e1.x - e3.x, e1.y - e3.y);
      float2 A3 = make_float2(-s1 * d13.x - c1 * d13.y, -s1 * d13.y + c1 * d13.x);
      Uf[a] = make_float2(A0.x + A1.x, A0.y + A1.y);
      float2 dB = make_float2(A0.x - A1.x, A0.y - A1.y);
      Uf[a + Hh] = make_float2(c2 * dB.x - s2 * dB.y, c2 * dB.y + s2 * dB.x);
      Uf[a + H] = make_float2(A2.x + A3.x, A2.y + A3.y);
      float2 dB2 = make_float2(A2.x - A3.x, A2.y - A3.y);
      Uf[a + H + Hh] = make_float2(c2 * dB2.x - s2 * dB2.y, c2 * dB2.y + s2 * dB2.x);
    }
    __syncthreads();
  }
  // de-scatter via LDS, then coalesced global stores
  #pragma unroll
  for (int f = 0; f < 2; ++f) {
    for (int i = tid; i < FFT_N; i += 512) {
      unsigned m = br10((unsigned)i);
      if (m < 512u) sout[f][m] = U[f][i].x;
    }
  }
  __syncthreads();
  {
    const float inv = 1.0f / (float)FFT_N;
    #pragma unroll
    for (int f = 0; f < 2; ++f)
      outw[(t0 + f) * WINL + tid] = sout[f][511 - tid] * inv * win[tid];
  }
}

// ---- K_D: overlap-add + 128-tap postfilter — verbatim ----
__global__ __launch_bounds__(256) void pf_k(const float* __restrict__ outw, const float* __restrict__ pf_w,
                                            const float* __restrict__ pf_b, float* __restrict__ y) {
  __shared__ float sb[256 + PF_KT - 1];
  __shared__ float wpf[PF_KT];
  int n0 = blockIdx.x * 256;
  for (int i = threadIdx.x; i < 256 + PF_KT - 1; i += 256) {
    int m = n0 - 63 + i;
    float v = 0.f;
    if (m >= 0 && m < ZLEN) {
      int t = m >> 8, j = m & 255;
      v = outw[t * WINL + j] + outw[((t - 1) & 255) * WINL + HOP + j];
    }
    sb[i] = v;
  }
  if (threadIdx.x < PF_KT) wpf[threadIdx.x] = pf_w[threadIdx.x];
  __syncthreads();
  float acc = pf_b[0];
  #pragma unroll 8
  for (int j = 0; j < PF_KT; ++j) acc += sb[threadIdx.x + j] * wpf[j];
  y[n0 + threadIdx.x] = acc;
}

extern "C" void kernel_launch(void* const* d_in, const int* in_sizes, int n_in,
                              void* d_out, int out_size, void* d_ws, size_t ws_size,
                              hipStream_t stream) {
  const float* x    = (const float*)d_in[0];
  const float* z    = (const float*)d_in[1];
  const float* w1   = (const float*)d_in[2];
  const float* b1   = (const float*)d_in[3];
  const float* w2   = (const float*)d_in[4];
  const float* b2   = (const float*)d_in[5];
  const float* w3   = (const float*)d_in[6];
  const float* b3   = (const float*)d_in[7];
  const float* pf_w = (const float*)d_in[8];
  const float* pf_b = (const float*)d_in[9];
  const float* quef = (const float*)d_in[10];
  const float* win  = (const float*)d_in[11];
  float* out = (float*)d_out;
  float* ws  = (float*)d_ws;

  // workspace layout (floats)
  float* h2p  = ws;                 // 16*256*256 = 1048576
  float* ccp  = h2p + 1048576;      // 16*256*222 = 909312
  float* outw = ccp + 909312;       // 256*512    = 131072

  conv12_k<<<dim3(16, 16), 512, 0, stream>>>(x, w1, b1, w2, h2p);
  conv3_k<<<dim3(16, 16), 512, 0, stream>>>(h2p, b2, w3, ccp);
  fftltv_k<<<T_FRAMES / 2, 512, 0, stream>>>(ccp, b3, quef, z, win, outw);
  pf_k<<<ZLEN / 256, 256, 0, stream>>>(outw, pf_w, pf_b, out);
}

// Round 26
// 30.658 us; speedup vs baseline: 1.0605x; 1.0605x over previous
//
#include <hip/hip_runtime.h>

#define T_FRAMES 256
#define D_IN 80
#define CCH 256
#define CCEP 222
#define FFT_N 1024
#define HOP 256
#define WINL 512
#define PF_KT 128
#define ZLEN 65536

__device__ __forceinline__ unsigned br10(unsigned x) { return __brev(x) >> 22; }

// =============== shared conv inner loop (512 thr: c = tid&255, fh = tid>>8, 8 frames each) ===============
__device__ __forceinline__ void conv_inner(const float4* __restrict__ wlds4,
                                           const float4* __restrict__ inlds4,
                                           int c, int fh, float* __restrict__ acc) {
  #pragma unroll
  for (int cg = 0; cg < 4; ++cg) {
    float4 w0 = wlds4[(cg * 3 + 0) * 256 + c];
    float4 w1v = wlds4[(cg * 3 + 1) * 256 + c];
    float4 w2v = wlds4[(cg * 3 + 2) * 256 + c];
    float4 xr[10];
    #pragma unroll
    for (int r = 0; r < 10; ++r) xr[r] = inlds4[(fh * 8 + r) * 4 + cg];
    #pragma unroll
    for (int j = 0; j < 8; ++j) {
      float4 xa = xr[j], xb = xr[j + 1], xc = xr[j + 2];
      acc[j] += xa.x * w0.x  + xb.x * w0.y  + xc.x * w0.z
              + xa.y * w0.w  + xb.y * w1v.x + xc.y * w1v.y
              + xa.z * w1v.z + xb.z * w1v.w + xc.z * w2v.x
              + xa.w * w2v.y + xb.w * w2v.z + xc.w * w2v.w;
    }
  }
}

// ---- K_A: fused conv1+conv2. grid (16 kc, 16 g) — coalesced weight staging ----
__global__ __launch_bounds__(512) void conv12_k(const float* __restrict__ x, const float* __restrict__ w1,
                                                const float* __restrict__ b1, const float* __restrict__ w2,
                                                float* __restrict__ h2p) {
  __shared__ float4 wlds4[12 * 256];   // w2 slice, 48 KB
  __shared__ float  w1lds[240 * 17];   // w1 slice, pitch 17 (conflict-free), 16 KB
  __shared__ float4 xlds4[20 * 20];    // x frames t0-2..t0+17
  __shared__ float4 inlds4[18 * 4];    // h1 chunk
  const int kc = blockIdx.x, g = blockIdx.y, tid = threadIdx.x;
  const int t0 = g << 4;
  const float4* w24 = (const float4*)w2;
  const float4* x4 = (const float4*)x;
  {
    const int row = tid & 255, seg = tid >> 8;
    const float4* src = w24 + row * 192 + kc * 12 + seg * 6;
    #pragma unroll
    for (int m = 0; m < 6; ++m) wlds4[(seg * 6 + m) * 256 + row] = src[m];
  }
  for (int idx = tid; idx < 3840; idx += 512) {
    int ch = idx / 240, j = idx - ch * 240;
    w1lds[j * 17 + ch] = w1[(kc * 16 + ch) * 240 + j];
  }
  if (tid < 400) {
    int f = tid / 20, cg = tid - f * 20;
    int tt = t0 - 2 + f;
    xlds4[f * 20 + cg] = (tt >= 0 && tt < T_FRAMES) ? x4[tt * 20 + cg] : make_float4(0.f, 0.f, 0.f, 0.f);
  }
  __syncthreads();
  if (tid < 288) {
    int f = tid >> 4, ch = tid & 15;
    int tt = t0 - 1 + f;
    float acc = b1[kc * 16 + ch];
    const float* x0 = (const float*)&xlds4[(f + 0) * 20];
    const float* x1 = (const float*)&xlds4[(f + 1) * 20];
    const float* x2 = (const float*)&xlds4[(f + 2) * 20];
    #pragma unroll 8
    for (int cin = 0; cin < D_IN; ++cin) {
      acc += x0[cin] * w1lds[(cin * 3 + 0) * 17 + ch]
           + x1[cin] * w1lds[(cin * 3 + 1) * 17 + ch]
           + x2[cin] * w1lds[(cin * 3 + 2) * 17 + ch];
    }
    ((float*)inlds4)[f * 16 + ch] = (tt >= 0 && tt < T_FRAMES) ? fmaxf(acc, 0.f) : 0.f;
  }
  __syncthreads();
  const int c = tid & 255, fh = tid >> 8;
  float acc[8] = {0.f, 0.f, 0.f, 0.f, 0.f, 0.f, 0.f, 0.f};
  conv_inner(wlds4, inlds4, c, fh, acc);
  const int ob = kc << 8;
  #pragma unroll
  for (int j = 0; j < 8; ++j) h2p[(ob + t0 + fh * 8 + j) * CCH + c] = acc[j];
}

// ---- K_B: conv3 partials. grid (16 kc, 16 g) — coalesced w3 staging + parallel sred ----
__global__ __launch_bounds__(512) void conv3_k(const float* __restrict__ h2p, const float* __restrict__ b2,
                                               const float* __restrict__ w3, float* __restrict__ ccp) {
  __shared__ float4 wlds4[12 * 256];
  __shared__ float4 sred4[72 * 4];
  __shared__ float4 inlds4[18 * 4];
  const int kc = blockIdx.x, g = blockIdx.y, tid = threadIdx.x;
  const int t0 = g << 4;
  const float4* w34 = (const float4*)w3;
  const float4* h2p4 = (const float4*)h2p;
  const float4* b24 = (const float4*)b2;
  {
    const int row = tid & 255, seg = tid >> 8;
    if (row < CCEP) {
      const float4* src = w34 + row * 192 + kc * 12 + seg * 6;
      #pragma unroll
      for (int m = 0; m < 6; ++m) wlds4[(seg * 6 + m) * 256 + row] = src[m];
    }
  }
  if (tid < 288) {
    int e = tid >> 2, q = tid & 3;
    int r = e >> 2, cg = e & 3;
    int tt = t0 - 1 + r;
    float4 v = make_float4(0.f, 0.f, 0.f, 0.f);
    if (tt >= 0 && tt < T_FRAMES) {
      #pragma unroll
      for (int pp = 0; pp < 4; ++pp) {
        float4 a = h2p4[(((q * 4 + pp) << 8) + tt) * 64 + kc * 4 + cg];
        v.x += a.x; v.y += a.y; v.z += a.z; v.w += a.w;
      }
    }
    sred4[e * 4 + q] = v;
  }
  __syncthreads();
  if (tid < 72) {
    int r = tid >> 2, cg = tid & 3, tt = t0 - 1 + r;
    float4 s = make_float4(0.f, 0.f, 0.f, 0.f);
    if (tt >= 0 && tt < T_FRAMES) {
      s = b24[kc * 4 + cg];
      #pragma unroll
      for (int q = 0; q < 4; ++q) {
        float4 v = sred4[tid * 4 + q];
        s.x += v.x; s.y += v.y; s.z += v.z; s.w += v.w;
      }
      s.x = fmaxf(s.x, 0.f); s.y = fmaxf(s.y, 0.f); s.z = fmaxf(s.z, 0.f); s.w = fmaxf(s.w, 0.f);
    }
    inlds4[tid] = s;
  }
  __syncthreads();
  const int c = tid & 255, fh = tid >> 8;
  if (c < CCEP) {
    float acc[8] = {0.f, 0.f, 0.f, 0.f, 0.f, 0.f, 0.f, 0.f};
    conv_inner(wlds4, inlds4, c, fh, acc);
    const int ob = kc << 8;
    #pragma unroll
    for (int j = 0; j < 8; ++j) ccp[(ob + t0 + fh * 8 + j) * CCEP + c] = acc[j];
  }
}

// ---- K_C: fused spectral kernel: coalesced reduction + LDS-staged z/out + radix-4 fused passes ----
__global__ __launch_bounds__(512) void fftltv_k(const float* __restrict__ ccp, const float* __restrict__ b3,
                                                const float* __restrict__ quef, const float* __restrict__ z,
                                                const float* __restrict__ win, float* __restrict__ outw) {
  __shared__ float2 U[FFT_N];
  __shared__ float ccs[224];
  __shared__ float zlds[512];
  __shared__ float sout[512];
  int t = blockIdx.x, tid = threadIdx.x;
  if (tid < CCEP) {
    float s = b3[tid];
    #pragma unroll
    for (int p = 0; p < 16; ++p) s += ccp[((p << 8) + t) * CCEP + tid];
    ccs[tid] = s / quef[tid];
  }
  {
    int idx = t * HOP + (int)tid - 255;
    zlds[tid] = (idx >= 0 && idx < ZLEN) ? z[idx] : 0.f;
  }
  __syncthreads();
  for (int i = tid; i < FFT_N; i += 512) {
    unsigned q = br10((unsigned)i);
    float a = (q >= 401u && q < 623u) ? ccs[q - 401u] : 0.f;
    float bv = (q < 512u) ? zlds[q] : 0.f;
    U[i] = make_float2(a, bv);
  }
  __syncthreads();
  #pragma unroll
  for (int s = 1; s <= 10; s += 2) {
    if (tid < 256) {
      int h = 1 << (s - 1);
      int pos = tid & (h - 1);
      int a = ((tid >> (s - 1)) << (s + 1)) + pos;
      float2 e0 = U[a], e1 = U[a + h], e2 = U[a + 2 * h], e3 = U[a + 3 * h];
      float s1, c1; __sincosf((-6.283185307179586f / (float)(2 * h)) * (float)pos, &s1, &c1);
      float s2, c2; __sincosf((-6.283185307179586f / (float)(4 * h)) * (float)pos, &s2, &c2);
      float2 t1 = make_float2(c1 * e1.x - s1 * e1.y, c1 * e1.y + s1 * e1.x);
      float2 t3 = make_float2(c1 * e3.x - s1 * e3.y, c1 * e3.y + s1 * e3.x);
      float2 A0 = make_float2(e0.x + t1.x, e0.y + t1.y);
      float2 A1 = make_float2(e0.x - t1.x, e0.y - t1.y);
      float2 A2 = make_float2(e2.x + t3.x, e2.y + t3.y);
      float2 A3 = make_float2(e2.x - t3.x, e2.y - t3.y);
      float2 u2 = make_float2(c2 * A2.x - s2 * A2.y, c2 * A2.y + s2 * A2.x);
      float2 u3 = make_float2(s2 * A3.x + c2 * A3.y, s2 * A3.y - c2 * A3.x);
      U[a]         = make_float2(A0.x + u2.x, A0.y + u2.y);
      U[a + 2 * h] = make_float2(A0.x - u2.x, A0.y - u2.y);
      U[a + h]     = make_float2(A1.x + u3.x, A1.y + u3.y);
      U[a + 3 * h] = make_float2(A1.x - u3.x, A1.y - u3.y);
    }
    __syncthreads();
  }
  {
    int j = tid;
    int mj = (FFT_N - j) & (FFT_N - 1);
    float2 Uj = U[j], Um = U[mj];
    float2 U5j = make_float2(0.f, 0.f);
    if (tid == 0) U5j = U[512];
    auto pcalc = [](float2 Uj, float2 Um) -> float2 {
      float Ar = 0.5f * (Uj.x + Um.x);
      float Ai = 0.5f * (Uj.y - Um.y);
      float Bx = 0.5f * (Uj.y + Um.y);
      float By = 0.5f * (Um.x - Uj.x);
      float mag = __expf(0.23025850929940457f * Ar);
      float sn, cs; __sincosf(Ai, &sn, &cs);
      float SPx = mag * cs, SPy = mag * sn;
      return make_float2(Bx * SPx + By * SPy, Bx * SPy - By * SPx);
    };
    float2 Pj = pcalc(Uj, Um);
    float2 P5 = (tid == 0) ? pcalc(U5j, U5j) : make_float2(0.f, 0.f);
    __syncthreads();
    U[j] = Pj;
    if (tid == 0) U[512] = P5;
    else U[mj] = make_float2(Pj.x, -Pj.y);
  }
  __syncthreads();
  #pragma unroll
  for (int s = 10; s >= 2; s -= 2) {
    if (tid < 256) {
      int H = 1 << (s - 1);
      int Hh = H >> 1;
      int pos = tid & (Hh - 1);
      int a = ((tid >> (s - 2)) << s) + pos;
      float2 e0 = U[a], e1 = U[a + Hh], e2 = U[a + H], e3 = U[a + H + Hh];
      float s1, c1; __sincosf((6.283185307179586f / (float)(2 * H)) * (float)pos, &s1, &c1);
      float s2, c2; __sincosf((6.283185307179586f / (float)H) * (float)pos, &s2, &c2);
      float2 A0 = make_float2(e0.x + e2.x, e0.y + e2.y);
      float2 d02 = make_float2(e0.x - e2.x, e0.y - e2.y);
      float2 A2 = make_float2(c1 * d02.x - s1 * d02.y, c1 * d02.y + s1 * d02.x);
      float2 A1 = make_float2(e1.x + e3.x, e1.y + e3.y);
      float2 d13 = make_float2(e1.x - e3.x, e1.y - e3.y);
      float2 A3 = make_float2(-s1 * d13.x - c1 * d13.y, -s1 * d13.y + c1 * d13.x);
      U[a] = make_float2(A0.x + A1.x, A0.y + A1.y);
      float2 dB = make_float2(A0.x - A1.x, A0.y - A1.y);
      U[a + Hh] = make_float2(c2 * dB.x - s2 * dB.y, c2 * dB.y + s2 * dB.x);
      U[a + H] = make_float2(A2.x + A3.x, A2.y + A3.y);
      float2 dB2 = make_float2(A2.x - A3.x, A2.y - A3.y);
      U[a + H + Hh] = make_float2(c2 * dB2.x - s2 * dB2.y, c2 * dB2.y + s2 * dB2.x);
    }
    __syncthreads();
  }
  for (int i = tid; i < FFT_N; i += 512) {
    unsigned m = br10((unsigned)i);
    if (m < 512u) sout[m] = U[i].x;
  }
  __syncthreads();
  {
    const float inv = 1.0f / (float)FFT_N;
    int w = tid;
    outw[t * WINL + w] = sout[511 - w] * inv * win[w];
  }
}

// ---- K_D: overlap-add (circular roll over t) + 128-tap postfilter ----
__global__ __launch_bounds__(256) void pf_k(const float* __restrict__ outw, const float* __restrict__ pf_w,
                                            const float* __restrict__ pf_b, float* __restrict__ y) {
  __shared__ float sb[256 + PF_KT - 1];
  __shared__ float wpf[PF_KT];
  int n0 = blockIdx.x * 256;
  for (int i = threadIdx.x; i < 256 + PF_KT - 1; i += 256) {
    int m = n0 - 63 + i;
    float v = 0.f;
    if (m >= 0 && m < ZLEN) {
      int t = m >> 8, j = m & 255;
      v = outw[t * WINL + j] + outw[((t - 1) & 255) * WINL + HOP + j];
    }
    sb[i] = v;
  }
  if (threadIdx.x < PF_KT) wpf[threadIdx.x] = pf_w[threadIdx.x];
  __syncthreads();
  float acc = pf_b[0];
  #pragma unroll 8
  for (int j = 0; j < PF_KT; ++j) acc += sb[threadIdx.x + j] * wpf[j];
  y[n0 + threadIdx.x] = acc;
}

extern "C" void kernel_launch(void* const* d_in, const int* in_sizes, int n_in,
                              void* d_out, int out_size, void* d_ws, size_t ws_size,
                              hipStream_t stream) {
  const float* x    = (const float*)d_in[0];
  const float* z    = (const float*)d_in[1];
  const float* w1   = (const float*)d_in[2];
  const float* b1   = (const float*)d_in[3];
  const float* w2   = (const float*)d_in[4];
  const float* b2   = (const float*)d_in[5];
  const float* w3   = (const float*)d_in[6];
  const float* b3   = (const float*)d_in[7];
  const float* pf_w = (const float*)d_in[8];
  const float* pf_b = (const float*)d_in[9];
  const float* quef = (const float*)d_in[10];
  const float* win  = (const float*)d_in[11];
  float* out = (float*)d_out;
  float* ws  = (float*)d_ws;

  // workspace layout (floats)
  float* h2p  = ws;                 // 16*256*256 = 1048576
  float* ccp  = h2p + 1048576;      // 16*256*222 = 909312
  float* outw = ccp + 909312;       // 256*512    = 131072

  conv12_k<<<dim3(16, 16), 512, 0, stream>>>(x, w1, b1, w2, h2p);
  conv3_k<<<dim3(16, 16), 512, 0, stream>>>(h2p, b2, w3, ccp);
  fftltv_k<<<T_FRAMES, 512, 0, stream>>>(ccp, b3, quef, z, win, outw);
  pf_k<<<ZLEN / 256, 256, 0, stream>>>(outw, pf_w, pf_b, out);
}